// Round 1
// baseline (1181.908 us; speedup 1.0000x reference)
//
#include <hip/hip_runtime.h>

// DSS (diagonal state space) forward:
//   y[b,h,t] = sum_{s<=t} K[h,s] * u[b,h,t-s] + D[h]*u[b,h,t],  masked t < length[b]
//   K[h,l] = 2*Re( sum_n Ct[h,n] * w[h,n]^l ),  w = exp(dt*A),  Ct = C*(exp(dt*A)-1)/A
// Computed exactly (no truncation) as a 64-complex-state linear recurrence:
//   x_n[t] = w_n * x_n[t-1] + u[t];  y[t] = 2*Re(sum_n Ct_n x_n[t]) + D*u[t]
// One wave per (b,h); lane = mode n (N=64 == wavefront size).

#define B_SZ 16
#define H_SZ 256
#define N_SZ 64
#define L_SZ 4096

__global__ __launch_bounds__(256) void dssm_scan_kernel(
    const float* __restrict__ u,          // (B,H,L)
    const float* __restrict__ log_dt,     // (H)
    const float* __restrict__ Cin,        // (H,N,2)
    const float* __restrict__ log_A_real, // (H,N)
    const float* __restrict__ A_imag,     // (H,N)
    const float* __restrict__ Dvec,       // (H)
    const int*   __restrict__ length,     // (B)
    float* __restrict__ y)                // (B,H,L)
{
    const int lane = threadIdx.x & 63;
    const int wave = blockIdx.x * (blockDim.x >> 6) + (threadIdx.x >> 6);
    if (wave >= B_SZ * H_SZ) return;
    const int b = wave / H_SZ;
    const int h = wave - b * H_SZ;
    const int n = lane;

    // ---- per-wave parameter setup (amortized over L=4096 steps) ----
    const float dt = expf(log_dt[h]);
    const float ar = expf(log_A_real[h * N_SZ + n]);   // A = -ar + i*ai
    const float ai = A_imag[h * N_SZ + n];
    const float dtre = -ar * dt;
    const float dtim =  ai * dt;
    const float er = expf(dtre);
    const float wr = er * cosf(dtim);                  // w = exp(dt*A)
    const float wi = er * sinf(dtim);
    // em1 = exp(dt*A) - 1
    const float em1r = wr - 1.0f;
    const float em1i = wi;
    // q = em1 / A = em1 * conj(A) / |A|^2 ; conj(A) = (-ar, -ai)
    const float inv = 1.0f / (ar * ar + ai * ai);
    const float qr = (em1i * ai - em1r * ar) * inv;
    const float qi = -(em1r * ai + em1i * ar) * inv;
    // Ct = Cc * q ; Cc = C[...,0] + i C[...,1]
    const float c0 = Cin[(h * N_SZ + n) * 2 + 0];
    const float c1 = Cin[(h * N_SZ + n) * 2 + 1];
    const float c2r = 2.0f * (c0 * qr - c1 * qi);      // fold the 2x into Ct
    const float c2i = 2.0f * (c0 * qi + c1 * qr);

    const float Dh = Dvec[h];
    const int   len = length[b];
    const long  base = ((long)b * H_SZ + h) * L_SZ;
    const float* up = u + base;
    float* yp = y + base;

    // ---- recurrence over time ----
    float xr = 0.0f, xi = 0.0f;
    for (int t0 = 0; t0 < L_SZ; t0 += 64) {
        const float uvec = up[t0 + lane];   // coalesced; lane j holds u[t0+j]
        float yv = 0.0f;
        #pragma unroll
        for (int j = 0; j < 64; ++j) {
            const float ut = __shfl(uvec, j, 64);      // broadcast u[t0+j]
            // x = w*x + u_t   (complex fma)
            const float nxr = fmaf(wr, xr, fmaf(-wi, xi, ut));
            const float nxi = fmaf(wi, xr, wr * xi);
            xr = nxr; xi = nxi;
            // per-lane contribution p = Re(2*Ct * x)
            float p = fmaf(c2r, xr, -c2i * xi);
            // wave-wide sum over the 64 modes
            #pragma unroll
            for (int m = 1; m < 64; m <<= 1) p += __shfl_xor(p, m, 64);
            if (lane == j) yv = p;                     // keep y[t0+lane]
        }
        const int t = t0 + lane;
        float out = yv + Dh * uvec;                    // + D*u
        out = (t < len) ? out : 0.0f;                  // length mask
        yp[t] = out;                                   // coalesced store
    }
}

extern "C" void kernel_launch(void* const* d_in, const int* in_sizes, int n_in,
                              void* d_out, int out_size, void* d_ws, size_t ws_size,
                              hipStream_t stream) {
    const float* u          = (const float*)d_in[0];
    const float* log_dt     = (const float*)d_in[1];
    const float* C          = (const float*)d_in[2];
    const float* log_A_real = (const float*)d_in[3];
    const float* A_imag     = (const float*)d_in[4];
    const float* D          = (const float*)d_in[5];
    const int*   length     = (const int*)d_in[6];
    float* y = (float*)d_out;

    const int waves = B_SZ * H_SZ;              // 4096 sequences
    const int block = 256;                      // 4 waves/block
    const int grid  = waves / (block / 64);     // 1024 blocks
    dssm_scan_kernel<<<grid, block, 0, stream>>>(u, log_dt, C, log_A_real,
                                                 A_imag, D, length, y);
}

// Round 2
// 376.741 us; speedup vs baseline: 3.1372x; 3.1372x over previous
//
#include <hip/hip_runtime.h>

// DSS (diagonal state space) forward as an exact 64-complex-mode recurrence:
//   x_n[t] = w_n * x_n[t-1] + u[t];  y[t] = 2*Re(sum_n Ct_n x_n[t]) + D*u[t]
// One wave per (b,h); lane = mode n (N=64 == wavefront size).
//
// Round-2 restructure: per 64-step chunk, each lane accumulates its
// contribution p[tau] for all 64 timesteps in registers, then a single
// reduce-scatter butterfly (6 stages, array-halving) sums over modes and
// leaves y[t0+tau] in lane tau -- coalesced store, no per-timestep serial
// reduction chain. Only remaining serial chain: the 2-FMA state update.

#define B_SZ 16
#define H_SZ 256
#define N_SZ 64
#define L_SZ 4096

__global__ __launch_bounds__(256) void dssm_scan_kernel(
    const float* __restrict__ u,          // (B,H,L)
    const float* __restrict__ log_dt,     // (H)
    const float* __restrict__ Cin,        // (H,N,2)
    const float* __restrict__ log_A_real, // (H,N)
    const float* __restrict__ A_imag,     // (H,N)
    const float* __restrict__ Dvec,       // (H)
    const int*   __restrict__ length,     // (B)
    float* __restrict__ y)                // (B,H,L)
{
    const int lane = threadIdx.x & 63;
    const int wave = blockIdx.x * (blockDim.x >> 6) + (threadIdx.x >> 6);
    if (wave >= B_SZ * H_SZ) return;
    const int b = wave / H_SZ;
    const int h = wave - b * H_SZ;
    const int n = lane;

    // ---- per-wave parameter setup (amortized over L=4096 steps) ----
    const float dt = expf(log_dt[h]);
    const float ar = expf(log_A_real[h * N_SZ + n]);   // A = -ar + i*ai
    const float ai = A_imag[h * N_SZ + n];
    const float dtre = -ar * dt;
    const float dtim =  ai * dt;
    const float er = expf(dtre);
    const float wr = er * cosf(dtim);                  // w = exp(dt*A)
    const float wi = er * sinf(dtim);
    const float em1r = wr - 1.0f;                      // exp(dt*A) - 1
    const float em1i = wi;
    // q = em1 / A ; conj(A) = (-ar, -ai)
    const float inv = 1.0f / (ar * ar + ai * ai);
    const float qr = (em1i * ai - em1r * ar) * inv;
    const float qi = -(em1r * ai + em1i * ar) * inv;
    // Ct = Cc * q, folded 2x
    const float c0 = Cin[(h * N_SZ + n) * 2 + 0];
    const float c1 = Cin[(h * N_SZ + n) * 2 + 1];
    const float c2r = 2.0f * (c0 * qr - c1 * qi);
    const float nc2i = -2.0f * (c0 * qi + c1 * qr);    // negated imag part
    const float nwi = -wi;

    const float Dh = Dvec[h];
    const int   len = length[b];
    const long  base = ((long)b * H_SZ + h) * L_SZ;
    const float* up = u + base;
    float* yp = y + base;

    float xr = 0.0f, xi = 0.0f;

    for (int t0 = 0; t0 < L_SZ; t0 += 64) {
        const float uvec = up[t0 + lane];   // coalesced; lane j holds u[t0+j]
        float p[64];

        // ---- fill: 64 steps of the mode recurrence, contributions to regs ----
        #pragma unroll
        for (int j = 0; j < 64; ++j) {
            const float ut = __shfl(uvec, j, 64);          // broadcast u[t0+j]
            const float nxr = fmaf(wr, xr, fmaf(nwi, xi, ut));
            const float nxi = fmaf(wi, xr, wr * xi);
            xr = nxr; xi = nxi;
            p[j] = fmaf(c2r, xr, nc2i * xi);               // Re(2*Ct*x)
        }

        // ---- reduce-scatter butterfly: y[tau] = sum_n p_n[tau] -> lane tau ----
        // Stage distance D: keep the half of p[] selected by (lane & D),
        // exchange the other half with lane^D. After 6 stages, lane n holds
        // the full mode-sum for timestep t0+n in p[0].
        #define RS_STAGE(D)                                        \
        {                                                          \
            const bool hi = (lane & (D)) != 0;                     \
            _Pragma("unroll")                                      \
            for (int i = 0; i < (D); ++i) {                        \
                const float a  = p[i];                             \
                const float bb = p[i + (D)];                       \
                const float send = hi ? a : bb;                    \
                const float keep = hi ? bb : a;                    \
                p[i] = keep + __shfl_xor(send, (D), 64);           \
            }                                                      \
        }
        RS_STAGE(32)
        RS_STAGE(16)
        RS_STAGE(8)
        RS_STAGE(4)
        RS_STAGE(2)
        RS_STAGE(1)
        #undef RS_STAGE

        const int t = t0 + lane;
        const float out = fmaf(Dh, uvec, p[0]);            // + D*u
        yp[t] = (t < len) ? out : 0.0f;                    // length mask
    }
}

extern "C" void kernel_launch(void* const* d_in, const int* in_sizes, int n_in,
                              void* d_out, int out_size, void* d_ws, size_t ws_size,
                              hipStream_t stream) {
    const float* u          = (const float*)d_in[0];
    const float* log_dt     = (const float*)d_in[1];
    const float* C          = (const float*)d_in[2];
    const float* log_A_real = (const float*)d_in[3];
    const float* A_imag     = (const float*)d_in[4];
    const float* D          = (const float*)d_in[5];
    const int*   length     = (const int*)d_in[6];
    float* y = (float*)d_out;

    const int waves = B_SZ * H_SZ;              // 4096 sequences
    const int block = 256;                      // 4 waves/block
    const int grid  = waves / (block / 64);     // 1024 blocks
    dssm_scan_kernel<<<grid, block, 0, stream>>>(u, log_dt, C, log_A_real,
                                                 A_imag, D, length, y);
}